// Round 1
// baseline (1069.210 us; speedup 1.0000x reference)
//
#include <hip/hip_runtime.h>
#include <hip/hip_bf16.h>
#include <math.h>

#define NN 50000
#define NE 800000
#define FD 128
#define CD 64
#define HD 128
#define LD 32

// ---------------- CSR build ----------------

__global__ void k_init_dis(float* dis, int n) {
    int i = blockIdx.x * blockDim.x + threadIdx.x;
    if (i < n) dis[i] = 1.0f;
}

__global__ void k_count(const int* __restrict__ col, float* dis, int e) {
    int i = blockIdx.x * blockDim.x + threadIdx.x;
    if (i < e) atomicAdd(&dis[col[i]], 1.0f);
}

// single-block scan: counts = (int)dis[i] - 1 (dis still holds degree incl. self loop)
__global__ void k_scan(const float* __restrict__ dis, int* off, int* curs, int n) {
    __shared__ int sums[1024];
    int t = threadIdx.x;
    int chunk = (n + 1023) / 1024;
    int s0 = t * chunk;
    int s = 0;
    for (int j = 0; j < chunk; j++) {
        int idx = s0 + j;
        if (idx < n) s += (int)dis[idx] - 1;
    }
    sums[t] = s;
    __syncthreads();
    for (int d = 1; d < 1024; d <<= 1) {
        int v = (t >= d) ? sums[t - d] : 0;
        __syncthreads();
        sums[t] += v;
        __syncthreads();
    }
    int run = (t == 0) ? 0 : sums[t - 1];
    for (int j = 0; j < chunk; j++) {
        int idx = s0 + j;
        if (idx < n) {
            off[idx] = run;
            curs[idx] = run;
            run += (int)dis[idx] - 1;
        }
    }
    if (t == 1023) off[n] = run;
}

__global__ void k_finish_dis(float* dis, int n) {
    int i = blockIdx.x * blockDim.x + threadIdx.x;
    if (i < n) dis[i] = rsqrtf(dis[i]);
}

__global__ void k_scatter(const int* __restrict__ row, const int* __restrict__ col,
                          int* curs, int* csr, int e) {
    int i = blockIdx.x * blockDim.x + threadIdx.x;
    if (i < e) {
        int c = col[i];
        int p = atomicAdd(&curs[c], 1);
        csr[p] = row[i];
    }
}

// ---------------- aggregation ----------------
// out[v] = dis[v] * sum_{r in in(v)} dis[r]*x[r]  +  dis[v]^2 * x[v]  (+ bias)

// pass 1: two sources (feature 128 | condition 64), width 192
__global__ void k_agg_fc(const float* __restrict__ feat, const float* __restrict__ cond,
                         const float* __restrict__ dis, const int* __restrict__ off,
                         const int* __restrict__ csr, float* __restrict__ out) {
    int v = blockIdx.x;
    int c = threadIdx.x;  // 0..191
    int o0 = off[v], o1 = off[v + 1];
    float acc = 0.0f;
    for (int k = o0; k < o1; k++) {
        int r = csr[k];
        float w = dis[r];
        float x = (c < FD) ? feat[(size_t)r * FD + c] : cond[(size_t)r * CD + (c - FD)];
        acc += w * x;
    }
    float dv = dis[v];
    float xs = (c < FD) ? feat[(size_t)v * FD + c] : cond[(size_t)v * CD + (c - FD)];
    out[(size_t)v * 192 + c] = dv * acc + dv * dv * xs;
}

template <int W, int NPB>
__global__ void k_agg(const float* __restrict__ x, const float* __restrict__ dis,
                      const int* __restrict__ off, const int* __restrict__ csr,
                      const float* __restrict__ bias, float* __restrict__ out, int n) {
    int v = blockIdx.x * NPB + threadIdx.x / W;
    int c = threadIdx.x % W;
    if (v >= n) return;
    int o0 = off[v], o1 = off[v + 1];
    float acc = 0.0f;
    for (int k = o0; k < o1; k++) {
        int r = csr[k];
        acc += dis[r] * x[(size_t)r * W + c];
    }
    float dv = dis[v];
    float res = dv * acc + dv * dv * x[(size_t)v * W + c];
    if (bias) res += bias[c];
    out[(size_t)v * W + c] = res;
}

// ---------------- GEMM: C = act(A @ W + b) ----------------
// A [n, lda] (use first K cols), W [K, M] row-major, C [n, ldo]
template <int ACT>
__global__ void k_gemm(const float* __restrict__ Ain, int lda, const float* __restrict__ Wm,
                       int K, int M, const float* __restrict__ bias, float* __restrict__ Cout,
                       int ldo, int n) {
    __shared__ float As[16][65];
    __shared__ float Bs[16][65];
    int bm = blockIdx.x * 64, bn = blockIdx.y * 64;
    int tid = threadIdx.x;
    int tx = tid & 15, ty = tid >> 4;
    float acc[4][4] = {};
    for (int k0 = 0; k0 < K; k0 += 16) {
        #pragma unroll
        for (int e = tid; e < 1024; e += 256) {
            int r = e >> 4, kk = e & 15;
            int rowg = bm + r;
            As[kk][r] = (rowg < n) ? Ain[(size_t)rowg * lda + k0 + kk] : 0.0f;
        }
        #pragma unroll
        for (int e = tid; e < 1024; e += 256) {
            int kk = e >> 6, c = e & 63;
            int cg = bn + c;
            Bs[kk][c] = (cg < M) ? Wm[(size_t)(k0 + kk) * M + cg] : 0.0f;
        }
        __syncthreads();
        #pragma unroll
        for (int kk = 0; kk < 16; kk++) {
            float a[4], b[4];
            #pragma unroll
            for (int i = 0; i < 4; i++) a[i] = As[kk][ty * 4 + i];
            #pragma unroll
            for (int j = 0; j < 4; j++) b[j] = Bs[kk][tx * 4 + j];
            #pragma unroll
            for (int i = 0; i < 4; i++)
                #pragma unroll
                for (int j = 0; j < 4; j++) acc[i][j] += a[i] * b[j];
        }
        __syncthreads();
    }
    #pragma unroll
    for (int i = 0; i < 4; i++) {
        int rowg = bm + ty * 4 + i;
        if (rowg >= n) continue;
        #pragma unroll
        for (int j = 0; j < 4; j++) {
            int cg = bn + tx * 4 + j;
            if (cg >= M) continue;
            float v = acc[i][j] + (bias ? bias[cg] : 0.0f);
            if (ACT) v = tanhf(v);
            Cout[(size_t)rowg * ldo + cg] = v;
        }
    }
}

// concat W_mean|W_logvar -> Wml [256,64]
__global__ void k_wml(const float* __restrict__ Wm, const float* __restrict__ Wl,
                      float* __restrict__ Wml) {
    int i = blockIdx.x * blockDim.x + threadIdx.x;  // 256*64
    if (i < 256 * 64) {
        int k = i >> 6, j = i & 63;
        Wml[i] = (j < 32) ? Wm[k * 32 + j] : Wl[k * 32 + (j - 32)];
    }
}

// z = noise * exp(0.5*logvar) + mean ; write z, mean, logvar to d_out
__global__ void k_z(const float* __restrict__ mlagg, const float* __restrict__ bm,
                    const float* __restrict__ bl, const float* __restrict__ noise,
                    float* __restrict__ zout, float* __restrict__ mout,
                    float* __restrict__ lout, int n) {
    int i = blockIdx.x * blockDim.x + threadIdx.x;  // n*32
    if (i >= n * LD) return;
    int v = i >> 5, c = i & 31;
    float m = mlagg[(size_t)v * 64 + c] + bm[c];
    float lv = mlagg[(size_t)v * 64 + 32 + c] + bl[c];
    mout[i] = m;
    lout[i] = lv;
    zout[i] = noise[i] * __expf(0.5f * lv) + m;
}

extern "C" void kernel_launch(void* const* d_in, const int* in_sizes, int n_in,
                              void* d_out, int out_size, void* d_ws, size_t ws_size,
                              hipStream_t stream) {
    const float* feature = (const float*)d_in[0];
    const float* condition = (const float*)d_in[1];
    const float* noise = (const float*)d_in[2];
    const float* W_f2h = (const float*)d_in[3];
    const float* b_f2h = (const float*)d_in[4];
    const float* W_c2h_e = (const float*)d_in[5];
    const float* b_c2h_e = (const float*)d_in[6];
    const float* W_mean = (const float*)d_in[7];
    const float* b_mean = (const float*)d_in[8];
    const float* W_logvar = (const float*)d_in[9];
    const float* b_logvar = (const float*)d_in[10];
    const float* W_z2h = (const float*)d_in[11];
    const float* b_z2h = (const float*)d_in[12];
    const float* W_c2h_d = (const float*)d_in[13];
    const float* b_c2h_d = (const float*)d_in[14];
    const float* W_out = (const float*)d_in[15];
    const float* b_out = (const float*)d_in[16];
    const int* ei = (const int*)d_in[17];
    const int* erow = ei;
    const int* ecol = ei + NE;

    // workspace layout (256B aligned segments)
    char* ws = (char*)d_ws;
    size_t p = 0;
    auto alloc = [&](size_t bytes) {
        size_t cur = p;
        p += (bytes + 255) & ~(size_t)255;
        return (void*)(ws + cur);
    };
    float* dis = (float*)alloc(NN * 4);
    int* off = (int*)alloc((NN + 1) * 4);
    int* curs = (int*)alloc(NN * 4);
    int* csr = (int*)alloc(NE * 4);
    float* Wml = (float*)alloc(256 * 64 * 4);
    float* B = (float*)alloc((size_t)NN * 192 * 4);  // P0 = agg([feat|cond])
    float* C = (float*)alloc((size_t)NN * 256 * 4);  // h then hd
    float* A = (float*)alloc((size_t)NN * 128 * 4);  // mlpre+mlagg / Pz / outpre
    float* A2 = A + (size_t)NN * 64;

    float* out_z = (float*)d_out;
    float* out_mean = out_z + (size_t)NN * LD;
    float* out_logvar = out_mean + (size_t)NN * LD;
    float* out_out = out_logvar + (size_t)NN * LD;

    const int TB = 256;
    // 1) degree + CSR
    hipLaunchKernelGGL(k_init_dis, dim3((NN + TB - 1) / TB), dim3(TB), 0, stream, dis, NN);
    hipLaunchKernelGGL(k_count, dim3((NE + TB - 1) / TB), dim3(TB), 0, stream, ecol, dis, NE);
    hipLaunchKernelGGL(k_scan, dim3(1), dim3(1024), 0, stream, dis, off, curs, NN);
    hipLaunchKernelGGL(k_finish_dis, dim3((NN + TB - 1) / TB), dim3(TB), 0, stream, dis, NN);
    hipLaunchKernelGGL(k_scatter, dim3((NE + TB - 1) / TB), dim3(TB), 0, stream, erow, ecol,
                       curs, csr, NE);

    // 2) P0 = agg([feature | condition])  [N,192]
    hipLaunchKernelGGL(k_agg_fc, dim3(NN), dim3(192), 0, stream, feature, condition, dis, off,
                       csr, B);

    dim3 g64x2((NN + 63) / 64, 2), g64x1((NN + 63) / 64, 1);
    // 3) h[:, :128] = tanh(P0[:, :128] @ W_f2h + b)
    hipLaunchKernelGGL(k_gemm<1>, g64x2, dim3(256), 0, stream, B, 192, W_f2h, 128, 128, b_f2h,
                       C, 256, NN);
    // 4) h[:, 128:] = tanh(P0[:, 128:] @ W_c2h_e + b)
    hipLaunchKernelGGL(k_gemm<1>, g64x2, dim3(256), 0, stream, B + 128, 192, W_c2h_e, 64, 128,
                       b_c2h_e, C + 128, 256, NN);
    // 5) mlpre = h @ [W_mean|W_logvar]   [N,64]
    hipLaunchKernelGGL(k_wml, dim3((256 * 64 + TB - 1) / TB), dim3(TB), 0, stream, W_mean,
                       W_logvar, Wml);
    hipLaunchKernelGGL(k_gemm<0>, g64x1, dim3(256), 0, stream, C, 256, Wml, 256, 64,
                       (const float*)nullptr, A, 64, NN);
    // 6) hd[:, 128:] = tanh(P0[:, 128:] @ W_c2h_d + b)   (overwrite c2h; h consumed)
    hipLaunchKernelGGL(k_gemm<1>, g64x2, dim3(256), 0, stream, B + 128, 192, W_c2h_d, 64, 128,
                       b_c2h_d, C + 128, 256, NN);
    // 7) mlagg = agg(mlpre)   [N,64]
    hipLaunchKernelGGL((k_agg<64, 1>), dim3(NN), dim3(64), 0, stream, A, dis, off, csr,
                       (const float*)nullptr, A2, NN);
    // 8) z, mean, logvar
    hipLaunchKernelGGL(k_z, dim3((NN * LD + TB - 1) / TB), dim3(TB), 0, stream, A2, b_mean,
                       b_logvar, noise, out_z, out_mean, out_logvar, NN);
    // 9) Pz = agg(z)   [N,32]
    hipLaunchKernelGGL((k_agg<32, 2>), dim3((NN + 1) / 2), dim3(64), 0, stream, out_z, dis, off,
                       csr, (const float*)nullptr, A, NN);
    // 10) hd[:, :128] = tanh(Pz @ W_z2h + b)
    hipLaunchKernelGGL(k_gemm<1>, g64x2, dim3(256), 0, stream, A, 32, W_z2h, 32, 128, b_z2h, C,
                       256, NN);
    // 11) outpre = hd @ W_out  [N,128]
    hipLaunchKernelGGL(k_gemm<0>, g64x2, dim3(256), 0, stream, C, 256, W_out, 256, 128,
                       (const float*)nullptr, A, 128, NN);
    // 12) out = agg(outpre) + b_out
    hipLaunchKernelGGL((k_agg<128, 1>), dim3(NN), dim3(128), 0, stream, A, dis, off, csr, b_out,
                       out_out, NN);
}